// Round 1
// 1121.094 us; speedup vs baseline: 1.0632x; 1.0632x over previous
//
#include <hip/hip_runtime.h>
#include <stdint.h>

// ---------------------------------------------------------------------------
// SelfAttention (pre-norm, shared-V) on MI355X / gfx950
// out  = (softmax((xn Wq^T)(xn Wk^T)^T / 16) @ xn) @ Wv^T + xn,  probs also output
// All GEMMs via v_mfma_f32_16x16x32_bf16, staging via global_load_lds width=16.
// Verified fragment maps (learn_hip m89/m120):
//   A-frag: A[m = lane&15][k = (lane>>4)*8 + j]
//   B-frag: B[n = lane&15][k = (lane>>4)*8 + j]   (BT form: both row-major, K inner)
//   C/D   : D[m = (lane>>4)*4 + r][n = lane&15]
// Round 1: 2-phase prefetch pipelining (issue next stage BEFORE compute, one
// barrier per phase) in attn_scores / gemm_bt / gemm_ctx; Q held in registers
// (2-deep pipeline) in attn_scores; XCD-bijective block swizzles.
// ---------------------------------------------------------------------------

typedef __bf16 bh8 __attribute__((ext_vector_type(8)));
typedef float f32x4 __attribute__((ext_vector_type(4)));

#define MFMA16(a, b, c) __builtin_amdgcn_mfma_f32_16x16x32_bf16((a), (b), (c), 0, 0, 0)

__device__ __forceinline__ uint16_t f2b(float f) {  // fp32 -> bf16 RNE
  uint32_t u = __float_as_uint(f);
  u += 0x7FFFu + ((u >> 16) & 1u);
  return (uint16_t)(u >> 16);
}
__device__ __forceinline__ uint32_t pack2(float a, float b) {
  return (uint32_t)f2b(a) | ((uint32_t)f2b(b) << 16);
}
// async global->LDS, 16B per lane; lds base must be wave-uniform (HW adds lane*16)
__device__ __forceinline__ void async16(const uint16_t* g, uint16_t* l) {
  __builtin_amdgcn_global_load_lds((__attribute__((address_space(1))) const uint32_t*)g,
                                   (__attribute__((address_space(3))) uint32_t*)l, 16, 0, 0);
}

// ---------------- LayerNorm: x -> xn fp32 (residual) + xn bf16 --------------
__global__ __launch_bounds__(256) void ln_kernel(
    const float* __restrict__ x, const float* __restrict__ gamma,
    const float* __restrict__ beta, float* __restrict__ xnf, uint16_t* __restrict__ xnb) {
  const int wave = threadIdx.x >> 6, lane = threadIdx.x & 63;
  const size_t row = (size_t)blockIdx.x * 4 + wave;  // one wave per 256-elem row
  const float4 v = *(const float4*)(x + row * 256 + lane * 4);
  float s = v.x + v.y + v.z + v.w;
  float ss = v.x * v.x + v.y * v.y + v.z * v.z + v.w * v.w;
#pragma unroll
  for (int d = 32; d; d >>= 1) { s += __shfl_xor(s, d); ss += __shfl_xor(ss, d); }
  const float mu = s * (1.0f / 256.0f);
  const float inv = rsqrtf(ss * (1.0f / 256.0f) - mu * mu + 1e-5f);
  const float4 g = *(const float4*)(gamma + lane * 4);
  const float4 be = *(const float4*)(beta + lane * 4);
  float4 o;
  o.x = (v.x - mu) * inv * g.x + be.x;
  o.y = (v.y - mu) * inv * g.y + be.y;
  o.z = (v.z - mu) * inv * g.z + be.z;
  o.w = (v.w - mu) * inv * g.w + be.w;
  *(float4*)(xnf + row * 256 + lane * 4) = o;
  ushort4 ob;
  ob.x = f2b(o.x); ob.y = f2b(o.y); ob.z = f2b(o.z); ob.w = f2b(o.w);
  *(ushort4*)(xnb + row * 256 + lane * 4) = ob;
}

// ---------------- fp32 -> bf16 weight conversion ----------------------------
__global__ __launch_bounds__(256) void cvt_kernel(const float* __restrict__ in,
                                                  uint16_t* __restrict__ out2, int n) {
  int i = blockIdx.x * 256 + threadIdx.x;
  if (i < n) out2[i] = f2b(in[i]);
}

// ---------------- xn (b,1024,256) -> xnT (b,256,1024) bf16 ------------------
__global__ __launch_bounds__(256) void transpose_xn(
    const uint16_t* __restrict__ xnb, uint16_t* __restrict__ xnT) {
  const int b = blockIdx.z, it = blockIdx.y, dt = blockIdx.x;  // 64x64 tiles
  __shared__ uint16_t tile[64][65];
  const int t = threadIdx.x;
  const int r = t >> 2, c0 = (t & 3) * 16;
  const uint16_t* src = xnb + ((size_t)b * 1024 + it * 64) * 256 + dt * 64;
#pragma unroll
  for (int i = 0; i < 16; ++i) tile[r][c0 + i] = src[(size_t)r * 256 + c0 + i];
  __syncthreads();
  uint16_t* dst = xnT + ((size_t)b * 256 + dt * 64) * 1024 + it * 64;
#pragma unroll
  for (int i = 0; i < 16; ++i) dst[(size_t)r * 1024 + c0 + i] = tile[c0 + i][r];
}

// ---------------- BT GEMM: C(MxN) = A(MxK) @ B(NxK)^T, 128x128 tile ---------
// RES=false: C bf16.  RES=true: C fp32 = acc + resid (residual add).
// 2-phase pipelined: stage(next) issued before compute(cur); one barrier/phase.
// Flat grid, XCD-bijective swizzle (nwg % 8 == 0; M is always 16384 -> 128 mt).
template <int K, int N, bool RES>
__global__ __launch_bounds__(256) void gemm_bt(
    const uint16_t* __restrict__ A, const uint16_t* __restrict__ B,
    void* __restrict__ Cv, const float* __restrict__ resid) {
  const int nwg = gridDim.x, cpx = nwg >> 3;
  const int lid = blockIdx.x;
  const int swz = (lid & 7) * cpx + (lid >> 3);
  const int m0 = (swz & 127) * 128, n0 = (swz >> 7) * 128;
  const int t = threadIdx.x;
  const int lane = t & 63, wave = t >> 6;
  const int l15 = lane & 15, quad = lane >> 4;
  const int wm = (wave >> 1) * 64, wn = (wave & 1) * 64;  // 2x2 waves of 64x64

  __shared__ uint16_t As[2][128 * 32];
  __shared__ uint16_t Bs[2][128 * 32];

  f32x4 acc[4][4];
#pragma unroll
  for (int mi = 0; mi < 4; ++mi)
#pragma unroll
    for (int ni = 0; ni < 4; ++ni)
#pragma unroll
      for (int r = 0; r < 4; ++r) acc[mi][ni][r] = 0.0f;

  auto stage = [&](int buf, int k0) {
#pragma unroll
    for (int j = 0; j < 2; ++j) {
      int cc = j * 256 + t;
      int row = cc >> 2, ko = (cc & 3) << 3;
      async16(A + (size_t)(m0 + row) * K + k0 + ko, &As[buf][(j * 256 + (t & ~63)) * 8]);
      async16(B + (size_t)(n0 + row) * K + k0 + ko, &Bs[buf][(j * 256 + (t & ~63)) * 8]);
    }
  };

  stage(0, 0);
  __syncthreads();
  int cur = 0;
  for (int k0 = 0; k0 < K; k0 += 32) {
    if (k0 + 32 < K) stage(cur ^ 1, k0 + 32);  // loads in flight across compute
    bh8 afr[4], bfr[4];
#pragma unroll
    for (int mi = 0; mi < 4; ++mi)
      afr[mi] = *(const bh8*)&As[cur][(wm + mi * 16 + l15) * 32 + quad * 8];
#pragma unroll
    for (int ni = 0; ni < 4; ++ni)
      bfr[ni] = *(const bh8*)&Bs[cur][(wn + ni * 16 + l15) * 32 + quad * 8];
#pragma unroll
    for (int mi = 0; mi < 4; ++mi)
#pragma unroll
      for (int ni = 0; ni < 4; ++ni) acc[mi][ni] = MFMA16(afr[mi], bfr[ni], acc[mi][ni]);
    __syncthreads();  // drains prefetch vmcnt(0) + protects buffer reuse
    cur ^= 1;
  }
#pragma unroll
  for (int mi = 0; mi < 4; ++mi)
#pragma unroll
    for (int ni = 0; ni < 4; ++ni)
#pragma unroll
      for (int r = 0; r < 4; ++r) {
        size_t m = (size_t)(m0 + wm + mi * 16 + quad * 4 + r);
        size_t n = (size_t)(n0 + wn + ni * 16 + l15);
        if constexpr (RES) {
          ((float*)Cv)[m * N + n] = acc[mi][ni][r] + resid[m * N + n];
        } else {
          ((uint16_t*)Cv)[m * N + n] = f2b(acc[mi][ni][r]);
        }
      }
}

// ---------------- fused scores + softmax ------------------------------------
// block = 32 Q-rows x full 1024 K-cols for one (b,h); 4 waves split columns.
// Q kept in registers (2-deep pipelined frag loads); K double-buffered in two
// 512x32 LDS halves with prefetch-before-compute (single barrier per phase).
// Flat 4096-block grid with XCD-bijective swizzle so one (b,h)'s 32 row-blocks
// share an XCD-L2 (K panel fetched ~once instead of ~8x).
__global__ __launch_bounds__(256, 2) void attn_scores(
    const uint16_t* __restrict__ Qp, const uint16_t* __restrict__ Kp,
    float* __restrict__ probs) {
  const int lid = blockIdx.x;            // nwg = 4096
  const int swz = (lid & 7) * 512 + (lid >> 3);
  const int z = swz >> 5, rb = swz & 31;
  const int b = z >> 3, h = z & 7;
  const int t = threadIdx.x;
  const int lane = t & 63, wave = t >> 6;
  const int l15 = lane & 15, quad = lane >> 4;
  const int m0 = rb * 32;

  const uint16_t* Qb = Qp + (size_t)b * 1024 * 2048 + (size_t)h * 256;
  const uint16_t* Kb = Kp + (size_t)b * 1024 * 2048 + (size_t)h * 256;

  __shared__ uint16_t Bs[2][512 * 32];  // 64 KB double-buffered K half-tiles
  __shared__ float redmax[32][4];
  __shared__ float redsum[32][4];

  f32x4 acc[2][16];
#pragma unroll
  for (int mi = 0; mi < 2; ++mi)
#pragma unroll
    for (int ni = 0; ni < 16; ++ni)
#pragma unroll
      for (int r = 0; r < 4; ++r) acc[mi][ni][r] = 0.0f;

  auto stageB = [&](int buf, int p) {
    const int k0 = (p >> 1) * 32, half = p & 1;
#pragma unroll
    for (int j = 0; j < 8; ++j) {
      int cc = j * 256 + t;
      int row = half * 512 + (cc >> 2), ko = (cc & 3) << 3;
      async16(Kb + (size_t)row * 2048 + k0 + ko, &Bs[buf][(j * 256 + (t & ~63)) * 8]);
    }
  };

  // Q fragments in registers, 2-deep pipeline (only 4 bh8 live at a time)
  bh8 aq[2][2];
#pragma unroll
  for (int mi = 0; mi < 2; ++mi)
    aq[0][mi] = *(const bh8*)(Qb + (size_t)(m0 + mi * 16 + l15) * 2048 + quad * 8);

  stageB(0, 0);
  __syncthreads();

  int cur = 0;
#pragma unroll
  for (int p = 0; p < 16; ++p) {
    const int ks = p >> 1, half = p & 1;
    if (half == 0 && ks < 7) {  // prefetch next k-step's Q frags (global, L2-hot)
#pragma unroll
      for (int mi = 0; mi < 2; ++mi)
        aq[(ks + 1) & 1][mi] =
            *(const bh8*)(Qb + (size_t)(m0 + mi * 16 + l15) * 2048 + (ks + 1) * 32 + quad * 8);
    }
    if (p < 15) stageB(cur ^ 1, p + 1);  // issue next K half-tile, stays in flight
#pragma unroll
    for (int ni = 0; ni < 8; ++ni) {
      bh8 bf = *(const bh8*)&Bs[cur][(wave * 128 + ni * 16 + l15) * 32 + quad * 8];
      acc[0][half * 8 + ni] = MFMA16(aq[ks & 1][0], bf, acc[0][half * 8 + ni]);
      acc[1][half * 8 + ni] = MFMA16(aq[ks & 1][1], bf, acc[1][half * 8 + ni]);
    }
    __syncthreads();
    cur ^= 1;
  }

  // softmax over each row's 1024 raw scores (scale 1/16 folded into exp2)
  const float sc = 0.0625f * 1.44269504f;
  float rowm[2][4];
#pragma unroll
  for (int mi = 0; mi < 2; ++mi)
#pragma unroll
    for (int r = 0; r < 4; ++r) {
      float m = acc[mi][0][r];
#pragma unroll
      for (int ni = 1; ni < 16; ++ni) m = fmaxf(m, acc[mi][ni][r]);
#pragma unroll
      for (int d = 1; d < 16; d <<= 1) m = fmaxf(m, __shfl_xor(m, d));
      rowm[mi][r] = m;
    }
  if (l15 == 0) {
#pragma unroll
    for (int mi = 0; mi < 2; ++mi)
#pragma unroll
      for (int r = 0; r < 4; ++r) redmax[mi * 16 + quad * 4 + r][wave] = rowm[mi][r];
  }
  __syncthreads();
#pragma unroll
  for (int mi = 0; mi < 2; ++mi)
#pragma unroll
    for (int r = 0; r < 4; ++r) {
      int row = mi * 16 + quad * 4 + r;
      rowm[mi][r] = fmaxf(fmaxf(redmax[row][0], redmax[row][1]),
                          fmaxf(redmax[row][2], redmax[row][3]));
    }
  float rsum[2][4];
#pragma unroll
  for (int mi = 0; mi < 2; ++mi)
#pragma unroll
    for (int r = 0; r < 4; ++r) rsum[mi][r] = 0.0f;
#pragma unroll
  for (int mi = 0; mi < 2; ++mi)
#pragma unroll
    for (int ni = 0; ni < 16; ++ni)
#pragma unroll
      for (int r = 0; r < 4; ++r) {
        float e = exp2f((acc[mi][ni][r] - rowm[mi][r]) * sc);
        acc[mi][ni][r] = e;
        rsum[mi][r] += e;
      }
#pragma unroll
  for (int mi = 0; mi < 2; ++mi)
#pragma unroll
    for (int r = 0; r < 4; ++r) {
#pragma unroll
      for (int d = 1; d < 16; d <<= 1) rsum[mi][r] += __shfl_xor(rsum[mi][r], d);
    }
  if (l15 == 0) {
#pragma unroll
    for (int mi = 0; mi < 2; ++mi)
#pragma unroll
      for (int r = 0; r < 4; ++r) redsum[mi * 16 + quad * 4 + r][wave] = rsum[mi][r];
  }
  __syncthreads();
  float rinv[2][4];
#pragma unroll
  for (int mi = 0; mi < 2; ++mi)
#pragma unroll
    for (int r = 0; r < 4; ++r) {
      int row = mi * 16 + quad * 4 + r;
      rinv[mi][r] = 1.0f / (redsum[row][0] + redsum[row][1] + redsum[row][2] + redsum[row][3]);
    }
  float* P = probs + (size_t)z * 1024 * 1024 + (size_t)m0 * 1024;
#pragma unroll
  for (int mi = 0; mi < 2; ++mi)
#pragma unroll
    for (int ni = 0; ni < 16; ++ni)
#pragma unroll
      for (int r = 0; r < 4; ++r) {
        int row = mi * 16 + quad * 4 + r;
        int col = (ni >> 3) * 512 + wave * 128 + (ni & 7) * 16 + l15;
        P[(size_t)row * 1024 + col] = acc[mi][ni][r] * rinv[mi][r];
      }
}

// ---------------- context GEMM: ctx(b,h) = probs(b,h) @ xn(b) ---------------
// A = probs fp32 (reg-staged + converted to bf16, T14 issue-early/write-late),
// B = xnT bf16 (async double-buffer). BM=64, BN=256 (probs read exactly once),
// 256 threads, 40 KB LDS -> 4 blocks/CU. Flat 2048-block grid, XCD swizzle.
__global__ __launch_bounds__(256) void gemm_ctx(
    const float* __restrict__ P, const uint16_t* __restrict__ XT,
    uint16_t* __restrict__ ctx) {
  const int lid = blockIdx.x;            // nwg = 2048
  const int swz = (lid & 7) * 256 + (lid >> 3);
  const int z = swz >> 4, mt = swz & 15;
  const int b = z >> 3, h = z & 7;
  const int t = threadIdx.x;
  const int lane = t & 63, wave = t >> 6;
  const int l15 = lane & 15, quad = lane >> 4;
  const int wm = (wave >> 1) * 32, wn = (wave & 1) * 128;  // 2x2 waves of 32x128
  const int m0 = mt * 64;
  const float* Ab = P + (size_t)z * 1024 * 1024;
  const uint16_t* Bb = XT + (size_t)b * 256 * 1024;

  __shared__ uint16_t As[2][64 * 32];    // 2 x 4 KB
  __shared__ uint16_t Bs[2][256 * 32];   // 2 x 16 KB

  f32x4 acc[2][8];
#pragma unroll
  for (int mi = 0; mi < 2; ++mi)
#pragma unroll
    for (int ni = 0; ni < 8; ++ni)
#pragma unroll
      for (int r = 0; r < 4; ++r) acc[mi][ni][r] = 0.0f;

  const int arow = t >> 2, aco = (t & 3) * 8;
  const float* ag = Ab + (size_t)(m0 + arow) * 1024 + aco;

  auto stageB = [&](int buf, int k0) {
#pragma unroll
    for (int j = 0; j < 4; ++j) {
      int cc = j * 256 + t;
      int row = cc >> 2, ko = (cc & 3) << 3;
      async16(Bb + (size_t)row * 1024 + k0 + ko, &Bs[buf][(j * 256 + (t & ~63)) * 8]);
    }
  };

  // prologue: k0 = 0
  {
    float4 f0 = *(const float4*)(ag);
    float4 f1 = *(const float4*)(ag + 4);
    stageB(0, 0);
    uint4 pk;
    pk.x = pack2(f0.x, f0.y); pk.y = pack2(f0.z, f0.w);
    pk.z = pack2(f1.x, f1.y); pk.w = pack2(f1.z, f1.w);
    *(uint4*)&As[0][arow * 32 + aco] = pk;
  }
  __syncthreads();

  int cur = 0;
  for (int k0 = 0; k0 < 1024; k0 += 32) {
    const bool nxt = (k0 + 32) < 1024;
    float4 g0, g1;
    if (nxt) {  // issue A loads first (vmcnt-ordered before B stage)
      g0 = *(const float4*)(ag + k0 + 32);
      g1 = *(const float4*)(ag + k0 + 36);
    }
    if (nxt) stageB(cur ^ 1, k0 + 32);
    bh8 afr[2], bfr[8];
#pragma unroll
    for (int mi = 0; mi < 2; ++mi)
      afr[mi] = *(const bh8*)&As[cur][(wm + mi * 16 + l15) * 32 + quad * 8];
#pragma unroll
    for (int ni = 0; ni < 8; ++ni)
      bfr[ni] = *(const bh8*)&Bs[cur][(wn + ni * 16 + l15) * 32 + quad * 8];
#pragma unroll
    for (int mi = 0; mi < 2; ++mi)
#pragma unroll
      for (int ni = 0; ni < 8; ++ni) acc[mi][ni] = MFMA16(afr[mi], bfr[ni], acc[mi][ni]);
    if (nxt) {  // write-late: A-load latency hidden under the MFMAs above
      uint4 pk;
      pk.x = pack2(g0.x, g0.y); pk.y = pack2(g0.z, g0.w);
      pk.z = pack2(g1.x, g1.y); pk.w = pack2(g1.z, g1.w);
      *(uint4*)&As[cur ^ 1][arow * 32 + aco] = pk;
    }
    __syncthreads();
    cur ^= 1;
  }
  const size_t growbase = (size_t)b * 1024 + m0 + wm;
#pragma unroll
  for (int mi = 0; mi < 2; ++mi)
#pragma unroll
    for (int ni = 0; ni < 8; ++ni)
#pragma unroll
      for (int r = 0; r < 4; ++r) {
        size_t grow = growbase + mi * 16 + quad * 4 + r;
        int col = h * 256 + wn + ni * 16 + l15;
        ctx[grow * 2048 + col] = f2b(acc[mi][ni][r]);
      }
}

// ---------------------------------------------------------------------------
extern "C" void kernel_launch(void* const* d_in, const int* in_sizes, int n_in,
                              void* d_out, int out_size, void* d_ws, size_t ws_size,
                              hipStream_t stream) {
  const float* x = (const float*)d_in[0];
  const float* Wq = (const float*)d_in[1];
  const float* Wk = (const float*)d_in[2];
  const float* Wv = (const float*)d_in[3];
  const float* gamma = (const float*)d_in[4];
  const float* beta = (const float*)d_in[5];
  float* out = (float*)d_out;
  float* probs = out + (size_t)16 * 1024 * 256;  // outputs concatenated: out, probs

  // workspace layout (bytes); total ~227 MB
  char* ws = (char*)d_ws;
  float* xnf = (float*)(ws + 0);                      // 16 MB fp32 xn (residual)
  uint16_t* xnb = (uint16_t*)(ws + 16777216);         // 8 MB  bf16 xn
  uint16_t* xnT = (uint16_t*)(ws + 25165824);         // 8 MB  bf16 xn^T per batch
  uint16_t* wqb = (uint16_t*)(ws + 33554432);         // 1 MB
  uint16_t* wkb = (uint16_t*)(ws + 34603008);         // 1 MB
  uint16_t* wvb = (uint16_t*)(ws + 35651584);         // 1 MB
  uint16_t* Qp = (uint16_t*)(ws + 36700160);          // 64 MB (16384 x 2048 bf16)
  uint16_t* Kp = (uint16_t*)(ws + 103809024);         // 64 MB
  uint16_t* ctx = (uint16_t*)(ws + 170917888);        // 64 MB

  ln_kernel<<<4096, 256, 0, stream>>>(x, gamma, beta, xnf, xnb);
  cvt_kernel<<<2048, 256, 0, stream>>>(Wq, wqb, 2048 * 256);
  cvt_kernel<<<2048, 256, 0, stream>>>(Wk, wkb, 2048 * 256);
  cvt_kernel<<<2048, 256, 0, stream>>>(Wv, wvb, 256 * 2048);
  transpose_xn<<<dim3(4, 16, 16), 256, 0, stream>>>(xnb, xnT);
  gemm_bt<256, 2048, false><<<2048, 256, 0, stream>>>(xnb, wqb, (void*)Qp, nullptr);
  gemm_bt<256, 2048, false><<<2048, 256, 0, stream>>>(xnb, wkb, (void*)Kp, nullptr);
  attn_scores<<<4096, 256, 0, stream>>>(Qp, Kp, probs);
  gemm_ctx<<<2048, 256, 0, stream>>>(probs, xnT, ctx);
  gemm_bt<2048, 256, true><<<256, 256, 0, stream>>>(ctx, wvb, (void*)out, xnf);
}

// Round 2
// 1008.646 us; speedup vs baseline: 1.1817x; 1.1115x over previous
//
#include <hip/hip_runtime.h>
#include <stdint.h>

// ---------------------------------------------------------------------------
// SelfAttention (pre-norm, shared-V) on MI355X / gfx950
// out  = (softmax((xn Wq^T)(xn Wk^T)^T / 16) @ xn) @ Wv^T + xn,  probs also output
// All GEMMs via v_mfma_f32_16x16x32_bf16, staging via global_load_lds width=16.
// Verified fragment maps (learn_hip m89/m120):
//   A-frag: A[m = lane&15][k = (lane>>4)*8 + j]
//   B-frag: B[n = lane&15][k = (lane>>4)*8 + j]   (BT form: both row-major, K inner)
//   C/D   : D[m = (lane>>4)*4 + r][n = lane&15]
// Round 2: fuse PV (ctx = probs @ xn) into the scores kernel — P stays on-chip
// (bf16 in LDS), probs written once with non-temporal stores (never re-read),
// gemm_ctx deleted. Saves the 512 MB fp32 probs re-read + a kernel's staging.
// ---------------------------------------------------------------------------

typedef __bf16 bh8 __attribute__((ext_vector_type(8)));
typedef float f32x4 __attribute__((ext_vector_type(4)));

#define MFMA16(a, b, c) __builtin_amdgcn_mfma_f32_16x16x32_bf16((a), (b), (c), 0, 0, 0)

__device__ __forceinline__ uint16_t f2b(float f) {  // fp32 -> bf16 RNE
  uint32_t u = __float_as_uint(f);
  u += 0x7FFFu + ((u >> 16) & 1u);
  return (uint16_t)(u >> 16);
}
__device__ __forceinline__ uint32_t pack2(float a, float b) {
  return (uint32_t)f2b(a) | ((uint32_t)f2b(b) << 16);
}
// async global->LDS, 16B per lane; lds base must be wave-uniform (HW adds lane*16)
__device__ __forceinline__ void async16(const uint16_t* g, uint16_t* l) {
  __builtin_amdgcn_global_load_lds((__attribute__((address_space(1))) const uint32_t*)g,
                                   (__attribute__((address_space(3))) uint32_t*)l, 16, 0, 0);
}

// ---------------- LayerNorm: x -> xn fp32 (residual) + xn bf16 --------------
__global__ __launch_bounds__(256) void ln_kernel(
    const float* __restrict__ x, const float* __restrict__ gamma,
    const float* __restrict__ beta, float* __restrict__ xnf, uint16_t* __restrict__ xnb) {
  const int wave = threadIdx.x >> 6, lane = threadIdx.x & 63;
  const size_t row = (size_t)blockIdx.x * 4 + wave;  // one wave per 256-elem row
  const float4 v = *(const float4*)(x + row * 256 + lane * 4);
  float s = v.x + v.y + v.z + v.w;
  float ss = v.x * v.x + v.y * v.y + v.z * v.z + v.w * v.w;
#pragma unroll
  for (int d = 32; d; d >>= 1) { s += __shfl_xor(s, d); ss += __shfl_xor(ss, d); }
  const float mu = s * (1.0f / 256.0f);
  const float inv = rsqrtf(ss * (1.0f / 256.0f) - mu * mu + 1e-5f);
  const float4 g = *(const float4*)(gamma + lane * 4);
  const float4 be = *(const float4*)(beta + lane * 4);
  float4 o;
  o.x = (v.x - mu) * inv * g.x + be.x;
  o.y = (v.y - mu) * inv * g.y + be.y;
  o.z = (v.z - mu) * inv * g.z + be.z;
  o.w = (v.w - mu) * inv * g.w + be.w;
  *(float4*)(xnf + row * 256 + lane * 4) = o;
  ushort4 ob;
  ob.x = f2b(o.x); ob.y = f2b(o.y); ob.z = f2b(o.z); ob.w = f2b(o.w);
  *(ushort4*)(xnb + row * 256 + lane * 4) = ob;
}

// ---------------- fp32 -> bf16 weight conversion ----------------------------
__global__ __launch_bounds__(256) void cvt_kernel(const float* __restrict__ in,
                                                  uint16_t* __restrict__ out2, int n) {
  int i = blockIdx.x * 256 + threadIdx.x;
  if (i < n) out2[i] = f2b(in[i]);
}

// ---------------- xn (b,1024,256) -> xnT (b,256,1024) bf16 ------------------
__global__ __launch_bounds__(256) void transpose_xn(
    const uint16_t* __restrict__ xnb, uint16_t* __restrict__ xnT) {
  const int b = blockIdx.z, it = blockIdx.y, dt = blockIdx.x;  // 64x64 tiles
  __shared__ uint16_t tile[64][65];
  const int t = threadIdx.x;
  const int r = t >> 2, c0 = (t & 3) * 16;
  const uint16_t* src = xnb + ((size_t)b * 1024 + it * 64) * 256 + dt * 64;
#pragma unroll
  for (int i = 0; i < 16; ++i) tile[r][c0 + i] = src[(size_t)r * 256 + c0 + i];
  __syncthreads();
  uint16_t* dst = xnT + ((size_t)b * 256 + dt * 64) * 1024 + it * 64;
#pragma unroll
  for (int i = 0; i < 16; ++i) dst[(size_t)r * 1024 + c0 + i] = tile[c0 + i][r];
}

// ---------------- BT GEMM: C(MxN) = A(MxK) @ B(NxK)^T, 128x128 tile ---------
// RES=false: C bf16.  RES=true: C fp32 = acc + resid (residual add).
// 2-phase pipelined: stage(next) issued before compute(cur); one barrier/phase.
// Flat grid, XCD-bijective swizzle (nwg % 8 == 0; M is always 16384 -> 128 mt).
template <int K, int N, bool RES>
__global__ __launch_bounds__(256) void gemm_bt(
    const uint16_t* __restrict__ A, const uint16_t* __restrict__ B,
    void* __restrict__ Cv, const float* __restrict__ resid) {
  const int nwg = gridDim.x, cpx = nwg >> 3;
  const int lid = blockIdx.x;
  const int swz = (lid & 7) * cpx + (lid >> 3);
  const int m0 = (swz & 127) * 128, n0 = (swz >> 7) * 128;
  const int t = threadIdx.x;
  const int lane = t & 63, wave = t >> 6;
  const int l15 = lane & 15, quad = lane >> 4;
  const int wm = (wave >> 1) * 64, wn = (wave & 1) * 64;  // 2x2 waves of 64x64

  __shared__ uint16_t As[2][128 * 32];
  __shared__ uint16_t Bs[2][128 * 32];

  f32x4 acc[4][4];
#pragma unroll
  for (int mi = 0; mi < 4; ++mi)
#pragma unroll
    for (int ni = 0; ni < 4; ++ni)
#pragma unroll
      for (int r = 0; r < 4; ++r) acc[mi][ni][r] = 0.0f;

  auto stage = [&](int buf, int k0) {
#pragma unroll
    for (int j = 0; j < 2; ++j) {
      int cc = j * 256 + t;
      int row = cc >> 2, ko = (cc & 3) << 3;
      async16(A + (size_t)(m0 + row) * K + k0 + ko, &As[buf][(j * 256 + (t & ~63)) * 8]);
      async16(B + (size_t)(n0 + row) * K + k0 + ko, &Bs[buf][(j * 256 + (t & ~63)) * 8]);
    }
  };

  stage(0, 0);
  __syncthreads();
  int cur = 0;
  for (int k0 = 0; k0 < K; k0 += 32) {
    if (k0 + 32 < K) stage(cur ^ 1, k0 + 32);  // loads in flight across compute
    bh8 afr[4], bfr[4];
#pragma unroll
    for (int mi = 0; mi < 4; ++mi)
      afr[mi] = *(const bh8*)&As[cur][(wm + mi * 16 + l15) * 32 + quad * 8];
#pragma unroll
    for (int ni = 0; ni < 4; ++ni)
      bfr[ni] = *(const bh8*)&Bs[cur][(wn + ni * 16 + l15) * 32 + quad * 8];
    __builtin_amdgcn_s_setprio(1);
#pragma unroll
    for (int mi = 0; mi < 4; ++mi)
#pragma unroll
      for (int ni = 0; ni < 4; ++ni) acc[mi][ni] = MFMA16(afr[mi], bfr[ni], acc[mi][ni]);
    __builtin_amdgcn_s_setprio(0);
    __syncthreads();  // drains prefetch vmcnt(0) + protects buffer reuse
    cur ^= 1;
  }
#pragma unroll
  for (int mi = 0; mi < 4; ++mi)
#pragma unroll
    for (int ni = 0; ni < 4; ++ni)
#pragma unroll
      for (int r = 0; r < 4; ++r) {
        size_t m = (size_t)(m0 + wm + mi * 16 + quad * 4 + r);
        size_t n = (size_t)(n0 + wn + ni * 16 + l15);
        if constexpr (RES) {
          ((float*)Cv)[m * N + n] = acc[mi][ni][r] + resid[m * N + n];
        } else {
          ((uint16_t*)Cv)[m * N + n] = f2b(acc[mi][ni][r]);
        }
      }
}

// ---------------- fused scores + softmax + PV -------------------------------
// block = 32 Q-rows x full 1024 K-cols for one (b,h); 4 waves split columns.
// QK phase: Q in registers (2-deep pipeline), K double-buffered 512x32 LDS
// halves with prefetch-before-compute. Softmax in registers. PV phase: P tile
// (32x512 per half) re-written to LDS as bf16, ctx += P_half @ xn_half with
// xnT streamed via double-buffered global_load_lds. probs written once with
// non-temporal fp32 stores (never re-read). gemm_ctx kernel eliminated.
__global__ __launch_bounds__(256, 2) void attn_fused(
    const uint16_t* __restrict__ Qp, const uint16_t* __restrict__ Kp,
    const uint16_t* __restrict__ XT, float* __restrict__ probs,
    uint16_t* __restrict__ ctx) {
  const int lid = blockIdx.x;            // nwg = 4096
  const int swz = (lid & 7) * 512 + (lid >> 3);
  const int z = swz >> 5, rb = swz & 31;
  const int b = z >> 3, h = z & 7;
  const int t = threadIdx.x;
  const int lane = t & 63, wave = t >> 6;
  const int l15 = lane & 15, quad = lane >> 4;
  const int m0 = rb * 32;

  const uint16_t* Qb = Qp + (size_t)b * 1024 * 2048 + (size_t)h * 256;
  const uint16_t* Kb = Kp + (size_t)b * 1024 * 2048 + (size_t)h * 256;
  const uint16_t* Xb = XT + (size_t)b * 256 * 1024;

  constexpr int PP = 520;  // P_lds pitch (u16); +8 pad breaks same-bank rows
  union U {
    uint16_t qkBs[2][512 * 32];                          // 64 KB (QK phase)
    struct { uint16_t P[32 * PP]; uint16_t Bx[2][256 * 32]; } pv;  // 33+32 KB
  };
  __shared__ U u;
  __shared__ float redmax[32][4];
  __shared__ float redsum[32][4];

  f32x4 acc[2][16];
#pragma unroll
  for (int mi = 0; mi < 2; ++mi)
#pragma unroll
    for (int ni = 0; ni < 16; ++ni)
#pragma unroll
      for (int r = 0; r < 4; ++r) acc[mi][ni][r] = 0.0f;

  auto stageB = [&](int buf, int p) {
    const int k0 = (p >> 1) * 32, half = p & 1;
#pragma unroll
    for (int j = 0; j < 8; ++j) {
      int cc = j * 256 + t;
      int row = half * 512 + (cc >> 2), ko = (cc & 3) << 3;
      async16(Kb + (size_t)row * 2048 + k0 + ko, &u.qkBs[buf][(j * 256 + (t & ~63)) * 8]);
    }
  };

  // Q fragments in registers, 2-deep pipeline (only 4 bh8 live at a time)
  bh8 aq[2][2];
#pragma unroll
  for (int mi = 0; mi < 2; ++mi)
    aq[0][mi] = *(const bh8*)(Qb + (size_t)(m0 + mi * 16 + l15) * 2048 + quad * 8);

  stageB(0, 0);
  __syncthreads();

  int cur = 0;
#pragma unroll
  for (int p = 0; p < 16; ++p) {
    const int ks = p >> 1, half = p & 1;
    if (half == 0 && ks < 7) {  // prefetch next k-step's Q frags (global, L2-hot)
#pragma unroll
      for (int mi = 0; mi < 2; ++mi)
        aq[(ks + 1) & 1][mi] =
            *(const bh8*)(Qb + (size_t)(m0 + mi * 16 + l15) * 2048 + (ks + 1) * 32 + quad * 8);
    }
    if (p < 15) stageB(cur ^ 1, p + 1);  // issue next K half-tile, stays in flight
    __builtin_amdgcn_s_setprio(1);
#pragma unroll
    for (int ni = 0; ni < 8; ++ni) {
      bh8 bf = *(const bh8*)&u.qkBs[cur][(wave * 128 + ni * 16 + l15) * 32 + quad * 8];
      acc[0][half * 8 + ni] = MFMA16(aq[ks & 1][0], bf, acc[0][half * 8 + ni]);
      acc[1][half * 8 + ni] = MFMA16(aq[ks & 1][1], bf, acc[1][half * 8 + ni]);
    }
    __builtin_amdgcn_s_setprio(0);
    __syncthreads();
    cur ^= 1;
  }

  // ---- softmax over each row's 1024 raw scores (scale 1/16 folded into exp2)
  const float sc = 0.0625f * 1.44269504f;
  float rowm[2][4];
#pragma unroll
  for (int mi = 0; mi < 2; ++mi)
#pragma unroll
    for (int r = 0; r < 4; ++r) {
      float m = acc[mi][0][r];
#pragma unroll
      for (int ni = 1; ni < 16; ++ni) m = fmaxf(m, acc[mi][ni][r]);
#pragma unroll
      for (int d = 1; d < 16; d <<= 1) m = fmaxf(m, __shfl_xor(m, d));
      rowm[mi][r] = m;
    }
  if (l15 == 0) {
#pragma unroll
    for (int mi = 0; mi < 2; ++mi)
#pragma unroll
      for (int r = 0; r < 4; ++r) redmax[mi * 16 + quad * 4 + r][wave] = rowm[mi][r];
  }
  __syncthreads();
#pragma unroll
  for (int mi = 0; mi < 2; ++mi)
#pragma unroll
    for (int r = 0; r < 4; ++r) {
      int row = mi * 16 + quad * 4 + r;
      rowm[mi][r] = fmaxf(fmaxf(redmax[row][0], redmax[row][1]),
                          fmaxf(redmax[row][2], redmax[row][3]));
    }
  float rsum[2][4];
#pragma unroll
  for (int mi = 0; mi < 2; ++mi)
#pragma unroll
    for (int r = 0; r < 4; ++r) rsum[mi][r] = 0.0f;
#pragma unroll
  for (int mi = 0; mi < 2; ++mi)
#pragma unroll
    for (int ni = 0; ni < 16; ++ni)
#pragma unroll
      for (int r = 0; r < 4; ++r) {
        float e = exp2f((acc[mi][ni][r] - rowm[mi][r]) * sc);
        acc[mi][ni][r] = e;
        rsum[mi][r] += e;
      }
#pragma unroll
  for (int mi = 0; mi < 2; ++mi)
#pragma unroll
    for (int r = 0; r < 4; ++r) {
#pragma unroll
      for (int d = 1; d < 16; d <<= 1) rsum[mi][r] += __shfl_xor(rsum[mi][r], d);
    }
  if (l15 == 0) {
#pragma unroll
    for (int mi = 0; mi < 2; ++mi)
#pragma unroll
      for (int r = 0; r < 4; ++r) redsum[mi * 16 + quad * 4 + r][wave] = rsum[mi][r];
  }
  __syncthreads();
  float rinv[2][4];
#pragma unroll
  for (int mi = 0; mi < 2; ++mi)
#pragma unroll
    for (int r = 0; r < 4; ++r) {
      int row = mi * 16 + quad * 4 + r;
      rinv[mi][r] = 1.0f / (redsum[row][0] + redsum[row][1] + redsum[row][2] + redsum[row][3]);
    }

  // ---- PV phase: ctx_tile(32x256) += P(32x1024) @ xn_b(1024x256) ----------
  float* Pg = probs + (size_t)z * 1024 * 1024 + (size_t)m0 * 1024;

  auto stageX = [&](int buf, int k0) {
#pragma unroll
    for (int j = 0; j < 4; ++j) {
      int cc = j * 256 + t;
      int row = cc >> 2, ko = (cc & 3) << 3;
      async16(Xb + (size_t)row * 1024 + k0 + ko, &u.pv.Bx[buf][(j * 256 + (t & ~63)) * 8]);
    }
  };

  f32x4 acc2[2][4];
#pragma unroll
  for (int mi = 0; mi < 2; ++mi)
#pragma unroll
    for (int ni = 0; ni < 4; ++ni)
#pragma unroll
      for (int r = 0; r < 4; ++r) acc2[mi][ni][r] = 0.0f;

  // write P half0: bf16 -> LDS (for PV A-frags), fp32 -> global (NT, final)
#pragma unroll
  for (int mi = 0; mi < 2; ++mi)
#pragma unroll
    for (int ni = 0; ni < 8; ++ni)
#pragma unroll
      for (int r = 0; r < 4; ++r) {
        int row = mi * 16 + quad * 4 + r;
        int colh = wave * 128 + ni * 16 + l15;
        float v = acc[mi][ni][r] * rinv[mi][r];
        __builtin_nontemporal_store(v, &Pg[(size_t)row * 1024 + colh]);
        u.pv.P[row * PP + colh] = f2b(v);
      }
  stageX(0, 0);
  __syncthreads();

  cur = 0;
#pragma unroll
  for (int ks = 0; ks < 16; ++ks) {  // half0: j = 0..511
    stageX(cur ^ 1, ks * 32 + 32);   // ks=15 prefetches k0=512 (half1 tile 0)
    bh8 pa0 = *(const bh8*)&u.pv.P[l15 * PP + ks * 32 + quad * 8];
    bh8 pa1 = *(const bh8*)&u.pv.P[(16 + l15) * PP + ks * 32 + quad * 8];
    __builtin_amdgcn_s_setprio(1);
#pragma unroll
    for (int ni = 0; ni < 4; ++ni) {
      bh8 bx = *(const bh8*)&u.pv.Bx[cur][(wave * 64 + ni * 16 + l15) * 32 + quad * 8];
      acc2[0][ni] = MFMA16(pa0, bx, acc2[0][ni]);
      acc2[1][ni] = MFMA16(pa1, bx, acc2[1][ni]);
    }
    __builtin_amdgcn_s_setprio(0);
    __syncthreads();
    cur ^= 1;
  }

  // write P half1 (overwrites P_lds; all half0 reads completed at last barrier)
#pragma unroll
  for (int mi = 0; mi < 2; ++mi)
#pragma unroll
    for (int ni = 0; ni < 8; ++ni)
#pragma unroll
      for (int r = 0; r < 4; ++r) {
        int row = mi * 16 + quad * 4 + r;
        int colh = wave * 128 + ni * 16 + l15;
        float v = acc[mi][8 + ni][r] * rinv[mi][r];
        __builtin_nontemporal_store(v, &Pg[(size_t)row * 1024 + 512 + colh]);
        u.pv.P[row * PP + colh] = f2b(v);
      }
  __syncthreads();

#pragma unroll
  for (int ks = 0; ks < 16; ++ks) {  // half1: j = 512..1023
    if (ks < 15) stageX(cur ^ 1, 512 + ks * 32 + 32);
    bh8 pa0 = *(const bh8*)&u.pv.P[l15 * PP + ks * 32 + quad * 8];
    bh8 pa1 = *(const bh8*)&u.pv.P[(16 + l15) * PP + ks * 32 + quad * 8];
    __builtin_amdgcn_s_setprio(1);
#pragma unroll
    for (int ni = 0; ni < 4; ++ni) {
      bh8 bx = *(const bh8*)&u.pv.Bx[cur][(wave * 64 + ni * 16 + l15) * 32 + quad * 8];
      acc2[0][ni] = MFMA16(pa0, bx, acc2[0][ni]);
      acc2[1][ni] = MFMA16(pa1, bx, acc2[1][ni]);
    }
    __builtin_amdgcn_s_setprio(0);
    __syncthreads();
    cur ^= 1;
  }

  // ctx epilogue: row = b*1024 + seq, col = h*256 + d  (bf16)
  const size_t growbase = (size_t)b * 1024 + m0;
#pragma unroll
  for (int mi = 0; mi < 2; ++mi)
#pragma unroll
    for (int ni = 0; ni < 4; ++ni)
#pragma unroll
      for (int r = 0; r < 4; ++r) {
        size_t grow = growbase + mi * 16 + quad * 4 + r;
        int col = h * 256 + wave * 64 + ni * 16 + l15;
        ctx[grow * 2048 + col] = f2b(acc2[mi][ni][r]);
      }
}

// ---------------------------------------------------------------------------
extern "C" void kernel_launch(void* const* d_in, const int* in_sizes, int n_in,
                              void* d_out, int out_size, void* d_ws, size_t ws_size,
                              hipStream_t stream) {
  const float* x = (const float*)d_in[0];
  const float* Wq = (const float*)d_in[1];
  const float* Wk = (const float*)d_in[2];
  const float* Wv = (const float*)d_in[3];
  const float* gamma = (const float*)d_in[4];
  const float* beta = (const float*)d_in[5];
  float* out = (float*)d_out;
  float* probs = out + (size_t)16 * 1024 * 256;  // outputs concatenated: out, probs

  // workspace layout (bytes); total ~227 MB
  char* ws = (char*)d_ws;
  float* xnf = (float*)(ws + 0);                      // 16 MB fp32 xn (residual)
  uint16_t* xnb = (uint16_t*)(ws + 16777216);         // 8 MB  bf16 xn
  uint16_t* xnT = (uint16_t*)(ws + 25165824);         // 8 MB  bf16 xn^T per batch
  uint16_t* wqb = (uint16_t*)(ws + 33554432);         // 1 MB
  uint16_t* wkb = (uint16_t*)(ws + 34603008);         // 1 MB
  uint16_t* wvb = (uint16_t*)(ws + 35651584);         // 1 MB
  uint16_t* Qp = (uint16_t*)(ws + 36700160);          // 64 MB (16384 x 2048 bf16)
  uint16_t* Kp = (uint16_t*)(ws + 103809024);         // 64 MB
  uint16_t* ctx = (uint16_t*)(ws + 170917888);        // 64 MB

  ln_kernel<<<4096, 256, 0, stream>>>(x, gamma, beta, xnf, xnb);
  cvt_kernel<<<2048, 256, 0, stream>>>(Wq, wqb, 2048 * 256);
  cvt_kernel<<<2048, 256, 0, stream>>>(Wk, wkb, 2048 * 256);
  cvt_kernel<<<2048, 256, 0, stream>>>(Wv, wvb, 256 * 2048);
  transpose_xn<<<dim3(4, 16, 16), 256, 0, stream>>>(xnb, xnT);
  gemm_bt<256, 2048, false><<<2048, 256, 0, stream>>>(xnb, wqb, (void*)Qp, nullptr);
  gemm_bt<256, 2048, false><<<2048, 256, 0, stream>>>(xnb, wkb, (void*)Kp, nullptr);
  attn_fused<<<4096, 256, 0, stream>>>(Qp, Kp, xnT, probs, ctx);
  gemm_bt<2048, 256, true><<<256, 256, 0, stream>>>(ctx, wvb, (void*)out, xnf);
}